// Round 17
// baseline (199.372 us; speedup 1.0000x reference)
//
#include <hip/hip_runtime.h>
#include <hip/hip_bf16.h>

// LocalSelfAttention: B=4, S=4096, E=1024, WINDOW=256, SCALE=0.125
// Algebra: scores_ij = (x G + u)_i . x_j (row-consts cancel in softmax),
//   G = Wq^T Wk, u = Wk^T bq.  Since attn rows sum to 1:
//   out = attn @ (x W2^T) + b2 + x,  W2 = Wo Wv, b2 = Wo bv + bo.
// Round 17: gemm_yv -> faithful 8-phase counted-vmcnt schedule (T3+T4),
//   256^2 tile, 8 waves, BK=64, full free/stage/deadline ledger (below).
//   attn/prep/small-gemm unchanged from r16.

typedef unsigned short u16;
typedef __attribute__((ext_vector_type(8))) short short8;   // 8 bf16
typedef __attribute__((ext_vector_type(4))) short short4v;  // 4 bf16 (8B)
typedef __attribute__((ext_vector_type(4))) float f32x4;

__device__ __forceinline__ u16 f2bf(float f) {
    __hip_bfloat16 h = __float2bfloat16(f);
    return __builtin_bit_cast(u16, h);
}

__device__ __forceinline__ void gl_lds16(const u16* g, u16* l) {
    __builtin_amdgcn_global_load_lds(
        (const __attribute__((address_space(1))) void*)g,
        (__attribute__((address_space(3))) void*)l,
        16, 0, 0);
}

// ---------------- fused prep: cast x | wcast (WqT,WkT,WvT,Wob) | u,b2 ----------------
__global__ void prep(const float* __restrict__ x, u16* __restrict__ xb,
                     const float* __restrict__ Wq, const float* __restrict__ Wk,
                     const float* __restrict__ Wv, const float* __restrict__ Wo,
                     u16* __restrict__ WqT, u16* __restrict__ WkT,
                     u16* __restrict__ WvT, u16* __restrict__ Wob,
                     const float* __restrict__ bq, const float* __restrict__ bv,
                     const float* __restrict__ bo,
                     float* __restrict__ u, float* __restrict__ b2)
{
    __shared__ float lt[64][65];
    const int t = threadIdx.x;
    const int blk = blockIdx.x;
    if (blk < 8192) {
        int i = (blk * 256 + t) * 8;
        const float4* s = (const float4*)(x + i);
        float4 a = s[0], b = s[1];
        short8 o;
        o[0] = (short)f2bf(a.x); o[1] = (short)f2bf(a.y); o[2] = (short)f2bf(a.z); o[3] = (short)f2bf(a.w);
        o[4] = (short)f2bf(b.x); o[5] = (short)f2bf(b.y); o[6] = (short)f2bf(b.z); o[7] = (short)f2bf(b.w);
        *(short8*)(xb + i) = o;
        return;
    }
    if (blk < 9216) {
        const int wb = blk - 8192;
        const int which = wb >> 8;
        const int bid = wb & 255;
        const int c0 = (bid & 15) * 64, r0 = (bid >> 4) * 64;
        const int tr = t >> 3, tc = (t & 7) * 8;
        const float* src = which == 0 ? Wq : which == 1 ? Wk : which == 2 ? Wv : Wo;
        if (which == 3) {
#pragma unroll
            for (int p = 0; p < 2; ++p) {
                int r = p * 32 + tr;
                const float* s = src + (size_t)(r0 + r) * 1024 + c0 + tc;
                float4 a = *(const float4*)s, b = *(const float4*)(s + 4);
                short8 o;
                o[0] = (short)f2bf(a.x); o[1] = (short)f2bf(a.y); o[2] = (short)f2bf(a.z); o[3] = (short)f2bf(a.w);
                o[4] = (short)f2bf(b.x); o[5] = (short)f2bf(b.y); o[6] = (short)f2bf(b.z); o[7] = (short)f2bf(b.w);
                *(short8*)(Wob + (size_t)(r0 + r) * 1024 + c0 + tc) = o;
            }
            return;
        }
        u16* dst = which == 0 ? WqT : which == 1 ? WkT : WvT;
#pragma unroll
        for (int p = 0; p < 2; ++p) {
            int r = p * 32 + tr;
            const float* s = src + (size_t)(r0 + r) * 1024 + c0 + tc;
            float4 a = *(const float4*)s, b = *(const float4*)(s + 4);
            lt[r][tc + 0] = a.x; lt[r][tc + 1] = a.y; lt[r][tc + 2] = a.z; lt[r][tc + 3] = a.w;
            lt[r][tc + 4] = b.x; lt[r][tc + 5] = b.y; lt[r][tc + 6] = b.z; lt[r][tc + 7] = b.w;
        }
        __syncthreads();
#pragma unroll
        for (int p = 0; p < 2; ++p) {
            int r = p * 32 + tr;
            short8 o;
#pragma unroll
            for (int j = 0; j < 8; ++j) o[j] = (short)f2bf(lt[tc + j][r]);
            *(short8*)(dst + (size_t)(c0 + r) * 1024 + r0 + tc) = o;
        }
        return;
    }
    {
        const int bid = blk - 9216;
        if (bid < 4) {
            int b = bid * 256 + t;
            float acc = 0.f;
            for (int o = 0; o < 1024; ++o) acc += Wk[(size_t)o * 1024 + b] * bq[o];
            u[b] = acc;
        } else {
            int n = (bid - 4) * 16 + (t >> 4);
            int l = t & 15;
            float acc = 0.f;
            for (int m = l; m < 1024; m += 16) acc += Wo[(size_t)n * 1024 + m] * bv[m];
#pragma unroll
            for (int s = 1; s < 16; s <<= 1) acc += __shfl_xor(acc, s, 64);
            if (l == 0) b2[n] = acc + bo[n];
        }
    }
}

// ---------------- dual small GEMM (1024^3): H = WkT @ WqT^T, W2 = Wob @ WvT^T ----------------
__global__ __launch_bounds__(256, 4) void gemm_small_dual(
    const u16* __restrict__ HA, const u16* __restrict__ HB, u16* __restrict__ HC,
    const u16* __restrict__ WA, const u16* __restrict__ WB, u16* __restrict__ WC)
{
    __shared__ __align__(16) u16 At[64 * 64], Bt[64 * 64];
    const bool sec = blockIdx.x >= 256;
    const u16* A = sec ? WA : HA;
    const u16* B = sec ? WB : HB;
    u16* C = sec ? WC : HC;
    const int bid = blockIdx.x & 255;
    const int m0 = (bid >> 4) * 64, n0 = (bid & 15) * 64;
    const int t = threadIdx.x, lane = t & 63, w = t >> 6;
    const int l15 = lane & 15, lk = lane >> 4;

    f32x4 acc[4];
#pragma unroll
    for (int m = 0; m < 4; ++m) acc[m] = (f32x4){0.f, 0.f, 0.f, 0.f};

    for (int k0 = 0; k0 < 1024; k0 += 64) {
        __syncthreads();
#pragma unroll
        for (int p = 0; p < 2; ++p) {
            int e = p * 2048 + t * 8;
            int row = e >> 6, col = e & 63;
            short8 va = *(const short8*)(A + (size_t)(m0 + row) * 1024 + k0 + col);
            *(short8*)((char*)At + row * 128 + ((col * 2) ^ ((row & 7) << 4))) = va;
            short8 vb = *(const short8*)(B + (size_t)(n0 + row) * 1024 + k0 + col);
            *(short8*)((char*)Bt + row * 128 + ((col * 2) ^ ((row & 7) << 4))) = vb;
        }
        __syncthreads();
#pragma unroll
        for (int ks = 0; ks < 2; ++ks) {
            int bc = ks * 64 + lk * 16;
            int brow = w * 16 + l15;
            short8 bfr = *(const short8*)((char*)Bt + brow * 128 + (bc ^ ((brow & 7) << 4)));
#pragma unroll
            for (int m = 0; m < 4; ++m) {
                int arow = m * 16 + l15;
                short8 af = *(const short8*)((char*)At + arow * 128 + (bc ^ ((arow & 7) << 4)));
                acc[m] = __builtin_amdgcn_mfma_f32_16x16x32_bf16(af, bfr, acc[m], 0, 0, 0);
            }
        }
    }
#pragma unroll
    for (int m = 0; m < 4; ++m)
#pragma unroll
        for (int r = 0; r < 4; ++r) {
            int row = m0 + m * 16 + lk * 4 + r;
            int col = n0 + w * 16 + l15;
            C[(size_t)row * 1024 + col] = f2bf(acc[m][r]);
        }
}

// ---------------- fused dual GEMM, 8-phase schedule: y = x@H + u ; v2t = (x@W2^T)^T ----------------
// 256^2 tile, BK=64, 8 waves (2M x 4N), LDS 128KB (A0,B0,A1,B1 each 32KB).
// Grid dim3(8,64) = 512 blocks; tn<4 -> y (Hb), tn>=4 -> v2 transposed (W2b).
// Iter j computes K-tiles t0=2j (buf0) in P1-P4 and t1=2j+1 (buf1) in P5-P8.
// Phase = {ds_reads, [stage], [vmcnt], s_barrier, lgkmcnt(0), 16 MFMA, s_barrier}.
//
// FREES (end-of-phase barriers): B0: P3 | A0: P4 | B1: P7 | A1: P8.
// STAGES (4 gl_lds each): P1(j>=1): A(2j+1)->A1 | P4: B(2j+2)->B0 |
//                         P5: A(2j+2)->A0      | P8: B(2j+3)->B1.
// Each stage lands in a region freed by the immediately preceding end-barrier;
// cross-wave WAR safe because phase-p readers retire (lgkmcnt0) before passing
// phase-p's END barrier, which precedes any later-phase stage issue.
// DEADLINES (vmcnt(4) at P4 and P8, after own stage):
//   P4's vmcnt -> P8(j-1) [B1] and P1(j) [A1] complete before P5-P8 reads.
//   P8's vmcnt -> P4(j) [B0] and P5(j) [A0] complete before P1-P4(j+1) reads.
// Prologue: stage tiles 0,1 (16 loads), vmcnt(8) [tile 0 ready], barrier;
//   tile 1 covered by P4(0)'s vmcnt(4).
__global__ __launch_bounds__(512) void gemm_yv(
    const u16* __restrict__ A, const u16* __restrict__ BH, const u16* __restrict__ BW,
    const float* __restrict__ ub, u16* __restrict__ Y, u16* __restrict__ V2t)
{
    __shared__ __align__(16) char smbuf[131072];
    char* A0 = smbuf;
    char* B0 = smbuf + 32768;
    char* A1 = smbuf + 65536;
    char* B1 = smbuf + 98304;

    const int t = threadIdx.x;
    const int lane = t & 63, w = t >> 6;
    const int l15 = lane & 15, lk = lane >> 4;
    const int wm = w >> 2, wn = w & 3;
    const int K = 1024;

    const int bid = blockIdx.y * 8 + blockIdx.x;   // nwg = 512
    const int swz = (bid & 7) * 64 + (bid >> 3);
    const int tn = swz & 7, tm = swz >> 3;
    const int m0 = tm * 256;
    const bool isv = tn >= 4;
    const int n0 = (tn & 3) * 256;
    const u16* B = isv ? BW : BH;

    const int srow = t >> 3;                 // 0..63
    const int scg = ((t & 7) ^ (srow & 7)) * 8;   // pre-swizzled source col

    f32x4 acc[8][4];
#pragma unroll
    for (int mf = 0; mf < 8; ++mf)
#pragma unroll
        for (int nf = 0; nf < 4; ++nf)
            acc[mf][nf] = (f32x4){0.f, 0.f, 0.f, 0.f};

    // full-tile stage: 256x64 bf16, 4 gl_lds/thread; dest linear, source pre-swizzled
    auto STAGE_T = [&](const u16* G, int gr0, int k0, char* dst) {
#pragma unroll
        for (int h = 0; h < 2; ++h)
#pragma unroll
            for (int c = 0; c < 2; ++c) {
                int ri = h * 128 + c * 64 + srow;
                gl_lds16(G + (size_t)(gr0 + ri) * K + k0 + scg,
                         (u16*)(dst + h * 16384 + c * 8192 + t * 16));
            }
    };
    auto RD = [&](const char* tile, int r, int kc) -> short8 {
        return *(const short8*)(tile + r * 128 + ((kc ^ (r & 7)) << 4));
    };

    short8 av[4], bv[4];
    auto LA = [&](const char* tA, int mfb, int ks) {
#pragma unroll
        for (int f = 0; f < 4; ++f)
            av[f] = RD(tA, wm * 128 + (mfb + f) * 16 + l15, ks * 4 + lk);
    };
    auto LB = [&](const char* tB, int ks) {
#pragma unroll
        for (int f = 0; f < 4; ++f)
            bv[f] = RD(tB, wn * 64 + f * 16 + l15, ks * 4 + lk);
    };
    auto MM = [&](int mfb) {
        __builtin_amdgcn_s_setprio(1);
#pragma unroll
        for (int f = 0; f < 4; ++f)
#pragma unroll
            for (int nf = 0; nf < 4; ++nf)
                acc[mfb + f][nf] = __builtin_amdgcn_mfma_f32_16x16x32_bf16(av[f], bv[nf], acc[mfb + f][nf], 0, 0, 0);
        __builtin_amdgcn_s_setprio(0);
    };
    auto BARW = [&] {
        __builtin_amdgcn_s_barrier();
        asm volatile("s_waitcnt lgkmcnt(0)" ::: "memory");
        __builtin_amdgcn_sched_barrier(0);
    };
    auto BARE = [&] {
        __builtin_amdgcn_s_barrier();
        __builtin_amdgcn_sched_barrier(0);
    };

    // prologue: tiles 0 and 1
    STAGE_T(A, m0, 0, A0);
    STAGE_T(B, n0, 0, B0);
    STAGE_T(A, m0, 64, A1);
    STAGE_T(B, n0, 64, B1);
    asm volatile("s_waitcnt vmcnt(8)" ::: "memory");   // tile 0 landed; tile 1 in flight
    __builtin_amdgcn_s_barrier();
    __builtin_amdgcn_sched_barrier(0);

    for (int j = 0; j < 8; ++j) {
        // P1
        LA(A0, 0, 0); LB(B0, 0);
        if (j >= 1) STAGE_T(A, m0, (2 * j + 1) * 64, A1);
        BARW(); MM(0); BARE();
        // P2
        LA(A0, 4, 0);
        BARW(); MM(4); BARE();
        // P3
        LA(A0, 0, 1); LB(B0, 1);
        BARW(); MM(0); BARE();
        // P4
        LA(A0, 4, 1);
        if (2 * j + 2 < 16) {
            STAGE_T(B, n0, (2 * j + 2) * 64, B0);
            asm volatile("s_waitcnt vmcnt(4)" ::: "memory");
        } else {
            asm volatile("s_waitcnt vmcnt(0)" ::: "memory");
        }
        BARW(); MM(4); BARE();
        // P5
        LA(A1, 0, 0); LB(B1, 0);
        if (2 * j + 2 < 16) STAGE_T(A, m0, (2 * j + 2) * 64, A0);
        BARW(); MM(0); BARE();
        // P6
        LA(A1, 4, 0);
        BARW(); MM(4); BARE();
        // P7
        LA(A1, 0, 1); LB(B1, 1);
        BARW(); MM(0); BARE();
        // P8
        LA(A1, 4, 1);
        if (2 * j + 3 < 16) {
            STAGE_T(B, n0, (2 * j + 3) * 64, B1);
            asm volatile("s_waitcnt vmcnt(4)" ::: "memory");
        } else {
            asm volatile("s_waitcnt vmcnt(0)" ::: "memory");
        }
        BARW(); MM(4); BARE();
    }

    if (!isv) {
#pragma unroll
        for (int mf = 0; mf < 8; ++mf)
#pragma unroll
            for (int nf = 0; nf < 4; ++nf) {
                int col = n0 + wn * 64 + nf * 16 + l15;
                float bvx = ub[col];
#pragma unroll
                for (int r = 0; r < 4; ++r) {
                    int row = m0 + wm * 128 + mf * 16 + lk * 4 + r;
                    Y[(size_t)row * 1024 + col] = f2bf(acc[mf][nf][r] + bvx);
                }
            }
    } else {
#pragma unroll
        for (int mf = 0; mf < 8; ++mf)
#pragma unroll
            for (int nf = 0; nf < 4; ++nf) {
                int col = n0 + wn * 64 + nf * 16 + l15;           // e index
                int row0 = m0 + wm * 128 + mf * 16 + lk * 4;      // i index base
                short4v pk;
#pragma unroll
                for (int r = 0; r < 4; ++r) pk[r] = (short)f2bf(acc[mf][nf][r]);
                *(short4v*)(V2t + (size_t)col * 16384 + row0) = pk;
            }
    }
}

// ---------------- windowed causal attention, double-buffered staging (r12, measured best) ----------------
__global__ __launch_bounds__(256, 1) void attn_win(
    const u16* __restrict__ y, const u16* __restrict__ xb,
    const u16* __restrict__ vt, const float* __restrict__ xres,
    const float* __restrict__ b2, float* __restrict__ outp)
{
    __shared__ __align__(16) char smem[116736];
    u16* P  = (u16*)(smem + 81920);
    float* rmax = (float*)(smem + 114688);
    float* rsum = (float*)(smem + 115712);

    const int t = threadIdx.x;
    const int lane = t & 63, wv = t >> 6;
    const int l15 = lane & 15, lk = lane >> 4;
    const int bid = blockIdx.x;
    const int swz = (bid & 7) * 32 + (bid >> 3);
    const int win = swz >> 2, qc = swz & 3;
    const size_t qrow0 = (size_t)win * 256 + qc * 64;
    const size_t krow0 = (size_t)win * 256;

    f32x4 acc[4][4];
#pragma unroll
    for (int m = 0; m < 4; ++m)
#pragma unroll
        for (int n = 0; n < 4; ++n)
            acc[m][n] = (f32x4){0.f, 0.f, 0.f, 0.f};

    short8 pq[2], pk[8];
    auto LOAD_QK = [&](int e0) {
#pragma unroll
        for (int p = 0; p < 2; ++p) {
            int e = p * 2048 + t * 8;
            pq[p] = *(const short8*)(y + (qrow0 + (e >> 6)) * 1024 + e0 + (e & 63));
        }
#pragma unroll
        for (int p = 0; p < 8; ++p) {
            int e = p * 2048 + t * 8;
            pk[p] = *(const short8*)(xb + (krow0 + (e >> 6)) * 1024 + e0 + (e & 63));
        }
    };
    auto WRITE_QK = [&](int b) {
        char* Qt = smem + b * 40960;
        char* Kt = Qt + 8192;
#pragma unroll
        for (int p = 0; p < 2; ++p) {
            int e = p * 2048 + t * 8;
            int row = e >> 6, col = e & 63;
            *(short8*)(Qt + row * 128 + ((col * 2) ^ ((row & 7) << 4))) = pq[p];
        }
#pragma unroll
        for (int p = 0; p < 8; ++p) {
            int e = p * 2048 + t * 8;
            int row = e >> 6, col = e & 63;
            *(short8*)(Kt + row * 128 + ((col * 2) ^ ((row & 7) << 4))) = pk[p];
        }
    };

    LOAD_QK(0);
    WRITE_QK(0);
    LOAD_QK(64);
    __syncthreads();

    for (int i = 0; i < 16; ++i) {
        const int b = i & 1;
        if (i + 1 < 16) {
            WRITE_QK(b ^ 1);
            if (i + 2 < 16) LOAD_QK((i + 2) * 64);
        }
        const char* Qt = smem + b * 40960;
        const char* Kt = Qt + 8192;
#pragma unroll
        for (int ks = 0; ks < 2; ++ks) {
            const int bc = ks * 64 + lk * 16;
            short8 af[4], bfr[4];
#pragma unroll
            for (int m = 0; m < 4; ++m) {
                int row = m * 16 + l15;
                af[m] = *(const short8*)(Qt + row * 128 + (bc ^ ((row & 7) << 4)));
            }
#pragma unroll
            for (int n = 0; n < 4; ++n) {
                int row = wv * 64 + n * 16 + l15;
                bfr[n] = *(const short8*)(Kt + row * 128 + (bc ^ ((row & 7) << 4)));
            }
            __builtin_amdgcn_s_setprio(1);
#pragma unroll
            for (int m = 0; m < 4; ++m)
#pragma unroll
                for (int n = 0; n < 4; ++n)
                    acc[m][n] = __builtin_amdgcn_mfma_f32_16x16x32_bf16(af[m], bfr[n], acc[m][n], 0, 0, 0);
            __builtin_amdgcn_s_setprio(0);
        }
        __syncthreads();
    }

    // register softmax
#pragma unroll
    for (int m = 0; m < 4; ++m)
#pragma unroll
        for (int n = 0; n < 4; ++n) {
            int col = wv * 64 + n * 16 + l15;
#pragma unroll
            for (int r = 0; r < 4; ++r) {
                int qpos = qc * 64 + m * 16 + lk * 4 + r;
                float v = acc[m][n][r] * 0.125f;
                acc[m][n][r] = (col <= qpos) ? v : -1e30f;
            }
        }
#pragma unroll
    for (int m = 0; m < 4; ++m)
#pragma unroll
        for (int r = 0; r < 4; ++r) {
            float tmx = fmaxf(fmaxf(acc[m][0][r], acc[m][1][r]), fmaxf(acc[m][2][r], acc[m][3][r]));
            tmx = fmaxf(tmx, __shfl_xor(tmx, 1));
            tmx = fmaxf(tmx, __shfl_xor(tmx, 2));
            tmx = fmaxf(tmx, __shfl_xor(tmx, 4));
            tmx = fmaxf(tmx, __shfl_xor(tmx, 8));
            if (l15 == 0) rmax[(m * 16 + lk * 4 + r) * 4 + wv] = tmx;
        }
    __syncthreads();
#pragma unroll
    for (int m = 0; m < 4; ++m)
#pragma unroll
        for (int r = 0; r < 4; ++r) {
            int row = m * 16 + lk * 4 + r;
            float m4 = fmaxf(fmaxf(rmax[row * 4], rmax[row * 4 + 1]),
                             fmaxf(rmax[row * 4 + 2], rmax[row * 4 + 3]));
            float s = 0.f;
#pragma unroll
            for (int n = 0; n < 4; ++n) {
                float e = __expf(acc[m][n][r] - m4);
                acc[m][n][r] = e;
                s += e;
            }
            s += __shfl_xor(s, 1);
            s += __shfl_xor(s, 2);
            s += __shfl_xor(s, 4);
            s += __shfl_xor(s, 8);
            if (l15 == 0) rsum[row * 4 + wv] = s;
        }
    __syncthreads();
#pragma unroll
    for (int m = 0; m < 4; ++m)
#pragma unroll
        for (int r = 0; r < 4; ++r) {
            int row = m * 16 + lk * 4 + r;
            float inv = 1.f / (rsum[row * 4] + rsum[row * 4 + 1] + rsum[row * 4 + 2] + rsum[row * 4 + 3]);
#pragma unroll
            for (int n = 0; n < 4; ++n) {
                int col = wv * 64 + n * 16 + l15;
                *(u16*)((char*)P + row * 512 + ((col * 2) ^ ((row & 7) << 4))) = f2bf(acc[m][n][r] * inv);
            }
        }

    // phase 3
    short8 pv[8];
    auto LOAD_V = [&](int n0) {
#pragma unroll
        for (int p = 0; p < 8; ++p) {
            int e = p * 2048 + t * 8;
            pv[p] = *(const short8*)(vt + (size_t)(n0 + (e >> 8)) * 16384 + win * 256 + (e & 255));
        }
    };
    auto WRITE_V = [&](int b) {
        char* Vl = smem + b * 40960;
#pragma unroll
        for (int p = 0; p < 8; ++p) {
            int e = p * 2048 + t * 8;
            int row = e >> 8, col = e & 255;
            *(short8*)(Vl + row * 512 + ((col * 2) ^ ((row & 7) << 4))) = pv[p];
        }
    };

    LOAD_V(0);
    WRITE_V(0);
    LOAD_V(64);
    __syncthreads();

    for (int i = 0; i < 16; ++i) {
        const int b = i & 1;
        const int n0 = i * 64;
        if (i + 1 < 16) {
            WRITE_V(b ^ 1);
            if (i + 2 < 16) LOAD_V((i + 2) * 64);
        }
        const char* Vl = smem + b * 40960;
        f32x4 acc2[4];
#pragma unroll
        for (int m = 0; m < 4; ++m) acc2[m] = (f32x4){0.f, 0.f, 0.f, 0.f};
#pragma unroll
        for (int ks = 0; ks < 8; ++ks) {
            const int bc = ks * 64 + lk * 16;
            short8 af[4];
#pragma unroll
            for (int m = 0; m < 4; ++m) {
                int row = m * 16 + l15;
                af[m] = *(const short8*)((char*)P + row * 512 + (bc ^ ((row & 7) << 4)));
            }
            int vrow = wv * 16 + l15;
            short8 bfr = *(const short8*)(Vl + vrow * 512 + (bc ^ ((vrow & 7) << 4)));
            __builtin_amdgcn_s_setprio(1);
#pragma unroll
            for (int m = 0; m < 4; ++m)
                acc2[m] = __builtin_amdgcn_mfma_f32_16x16x32_bf16(af[m], bfr, acc2[m], 0, 0, 0);
            __builtin_amdgcn_s_setprio(0);
        }
#pragma unroll
        for (int m = 0; m < 4; ++m) {
#pragma unroll
            for (int r = 0; r < 4; ++r) {
                int row = m * 16 + lk * 4 + r;
                int col = n0 + wv * 16 + l15;
                size_t idx = (qrow0 + row) * 1024 + col;
                outp[idx] = acc2[m][r] + b2[col] + xres[idx];
            }
        }
        __syncthreads();
    }
}

extern "C" void kernel_launch(void* const* d_in, const int* in_sizes, int n_in,
                              void* d_out, int out_size, void* d_ws, size_t ws_size,
                              hipStream_t stream) {
    const float* x  = (const float*)d_in[0];
    const float* Wq = (const float*)d_in[1];
    const float* bq = (const float*)d_in[2];
    const float* Wk = (const float*)d_in[3];
    // bk (d_in[4]) contributes only row-constants to scores -> cancels in softmax
    const float* Wv = (const float*)d_in[5];
    const float* bv = (const float*)d_in[6];
    const float* Wo = (const float*)d_in[7];
    const float* bo = (const float*)d_in[8];
    float* out = (float*)d_out;

    char* ws = (char*)d_ws;
    u16* xb  = (u16*)(ws);                    // [16384,1024] bf16
    u16* yb  = (u16*)(ws + 33554432);         // [16384,1024] bf16
    u16* v2t = (u16*)(ws + 67108864);         // [1024,16384] bf16 (v2 transposed)
    u16* WqT = (u16*)(ws + 100663296);        // [1024,1024] bf16
    u16* WkT = (u16*)(ws + 102760448);        // [1024,1024] bf16
    u16* WvT = (u16*)(ws + 104857600);        // [1024,1024] bf16
    u16* Wob = (u16*)(ws + 106954752);        // [1024,1024] bf16
    u16* Hb  = (u16*)(ws + 109051904);        // [1024,1024] bf16 H = Wk^T Wq
    u16* W2b = (u16*)(ws + 111149056);        // [1024,1024] bf16 W2 = Wo Wv
    float* u_  = (float*)(ws + 113246208);    // [1024] fp32
    float* b2_ = (float*)(ws + 113250304);    // [1024] fp32

    prep<<<9284, 256, 0, stream>>>(x, xb, Wq, Wk, Wv, Wo, WqT, WkT, WvT, Wob,
                                   bq, bv, bo, u_, b2_);
    gemm_small_dual<<<512, 256, 0, stream>>>(WkT, WqT, Hb, Wob, WvT, W2b);
    gemm_yv<<<dim3(8, 64), 512, 0, stream>>>(xb, Hb, W2b, u_, yb, v2t);
    attn_win<<<256, 256, 0, stream>>>(yb, xb, v2t, x, b2_, out);
}

// Round 18
// 192.250 us; speedup vs baseline: 1.0370x; 1.0370x over previous
//
#include <hip/hip_runtime.h>
#include <hip/hip_bf16.h>

// LocalSelfAttention: B=4, S=4096, E=1024, WINDOW=256, SCALE=0.125
// Algebra: scores_ij = (x G + u)_i . x_j (row-consts cancel in softmax),
//   G = Wq^T Wk, u = Wk^T bq.  Since attn rows sum to 1:
//   out = attn @ (x W2^T) + b2 + x,  W2 = Wo Wv, b2 = Wo bv + bo.
// Round 18: attn causal load-balancing — each block handles paired 32-row
//   q-chunks (c, 7-c) of one window; kv-extents (c+1)*32 / (8-c)*32 sum to a
//   uniform 9 units -> 56% of the masked-tile MFMA work, balanced blocks.
//   gemm_yv = r17 8-phase; prep/small-gemm unchanged.

typedef unsigned short u16;
typedef __attribute__((ext_vector_type(8))) short short8;   // 8 bf16
typedef __attribute__((ext_vector_type(4))) short short4v;  // 4 bf16 (8B)
typedef __attribute__((ext_vector_type(4))) float f32x4;

__device__ __forceinline__ u16 f2bf(float f) {
    __hip_bfloat16 h = __float2bfloat16(f);
    return __builtin_bit_cast(u16, h);
}

__device__ __forceinline__ void gl_lds16(const u16* g, u16* l) {
    __builtin_amdgcn_global_load_lds(
        (const __attribute__((address_space(1))) void*)g,
        (__attribute__((address_space(3))) void*)l,
        16, 0, 0);
}

// ---------------- fused prep: cast x | wcast (WqT,WkT,WvT,Wob) | u,b2 ----------------
__global__ void prep(const float* __restrict__ x, u16* __restrict__ xb,
                     const float* __restrict__ Wq, const float* __restrict__ Wk,
                     const float* __restrict__ Wv, const float* __restrict__ Wo,
                     u16* __restrict__ WqT, u16* __restrict__ WkT,
                     u16* __restrict__ WvT, u16* __restrict__ Wob,
                     const float* __restrict__ bq, const float* __restrict__ bv,
                     const float* __restrict__ bo,
                     float* __restrict__ u, float* __restrict__ b2)
{
    __shared__ float lt[64][65];
    const int t = threadIdx.x;
    const int blk = blockIdx.x;
    if (blk < 8192) {
        int i = (blk * 256 + t) * 8;
        const float4* s = (const float4*)(x + i);
        float4 a = s[0], b = s[1];
        short8 o;
        o[0] = (short)f2bf(a.x); o[1] = (short)f2bf(a.y); o[2] = (short)f2bf(a.z); o[3] = (short)f2bf(a.w);
        o[4] = (short)f2bf(b.x); o[5] = (short)f2bf(b.y); o[6] = (short)f2bf(b.z); o[7] = (short)f2bf(b.w);
        *(short8*)(xb + i) = o;
        return;
    }
    if (blk < 9216) {
        const int wb = blk - 8192;
        const int which = wb >> 8;
        const int bid = wb & 255;
        const int c0 = (bid & 15) * 64, r0 = (bid >> 4) * 64;
        const int tr = t >> 3, tc = (t & 7) * 8;
        const float* src = which == 0 ? Wq : which == 1 ? Wk : which == 2 ? Wv : Wo;
        if (which == 3) {
#pragma unroll
            for (int p = 0; p < 2; ++p) {
                int r = p * 32 + tr;
                const float* s = src + (size_t)(r0 + r) * 1024 + c0 + tc;
                float4 a = *(const float4*)s, b = *(const float4*)(s + 4);
                short8 o;
                o[0] = (short)f2bf(a.x); o[1] = (short)f2bf(a.y); o[2] = (short)f2bf(a.z); o[3] = (short)f2bf(a.w);
                o[4] = (short)f2bf(b.x); o[5] = (short)f2bf(b.y); o[6] = (short)f2bf(b.z); o[7] = (short)f2bf(b.w);
                *(short8*)(Wob + (size_t)(r0 + r) * 1024 + c0 + tc) = o;
            }
            return;
        }
        u16* dst = which == 0 ? WqT : which == 1 ? WkT : WvT;
#pragma unroll
        for (int p = 0; p < 2; ++p) {
            int r = p * 32 + tr;
            const float* s = src + (size_t)(r0 + r) * 1024 + c0 + tc;
            float4 a = *(const float4*)s, b = *(const float4*)(s + 4);
            lt[r][tc + 0] = a.x; lt[r][tc + 1] = a.y; lt[r][tc + 2] = a.z; lt[r][tc + 3] = a.w;
            lt[r][tc + 4] = b.x; lt[r][tc + 5] = b.y; lt[r][tc + 6] = b.z; lt[r][tc + 7] = b.w;
        }
        __syncthreads();
#pragma unroll
        for (int p = 0; p < 2; ++p) {
            int r = p * 32 + tr;
            short8 o;
#pragma unroll
            for (int j = 0; j < 8; ++j) o[j] = (short)f2bf(lt[tc + j][r]);
            *(short8*)(dst + (size_t)(c0 + r) * 1024 + r0 + tc) = o;
        }
        return;
    }
    {
        const int bid = blk - 9216;
        if (bid < 4) {
            int b = bid * 256 + t;
            float acc = 0.f;
            for (int o = 0; o < 1024; ++o) acc += Wk[(size_t)o * 1024 + b] * bq[o];
            u[b] = acc;
        } else {
            int n = (bid - 4) * 16 + (t >> 4);
            int l = t & 15;
            float acc = 0.f;
            for (int m = l; m < 1024; m += 16) acc += Wo[(size_t)n * 1024 + m] * bv[m];
#pragma unroll
            for (int s = 1; s < 16; s <<= 1) acc += __shfl_xor(acc, s, 64);
            if (l == 0) b2[n] = acc + bo[n];
        }
    }
}

// ---------------- dual small GEMM (1024^3): H = WkT @ WqT^T, W2 = Wob @ WvT^T ----------------
__global__ __launch_bounds__(256, 4) void gemm_small_dual(
    const u16* __restrict__ HA, const u16* __restrict__ HB, u16* __restrict__ HC,
    const u16* __restrict__ WA, const u16* __restrict__ WB, u16* __restrict__ WC)
{
    __shared__ __align__(16) u16 At[64 * 64], Bt[64 * 64];
    const bool sec = blockIdx.x >= 256;
    const u16* A = sec ? WA : HA;
    const u16* B = sec ? WB : HB;
    u16* C = sec ? WC : HC;
    const int bid = blockIdx.x & 255;
    const int m0 = (bid >> 4) * 64, n0 = (bid & 15) * 64;
    const int t = threadIdx.x, lane = t & 63, w = t >> 6;
    const int l15 = lane & 15, lk = lane >> 4;

    f32x4 acc[4];
#pragma unroll
    for (int m = 0; m < 4; ++m) acc[m] = (f32x4){0.f, 0.f, 0.f, 0.f};

    for (int k0 = 0; k0 < 1024; k0 += 64) {
        __syncthreads();
#pragma unroll
        for (int p = 0; p < 2; ++p) {
            int e = p * 2048 + t * 8;
            int row = e >> 6, col = e & 63;
            short8 va = *(const short8*)(A + (size_t)(m0 + row) * 1024 + k0 + col);
            *(short8*)((char*)At + row * 128 + ((col * 2) ^ ((row & 7) << 4))) = va;
            short8 vb = *(const short8*)(B + (size_t)(n0 + row) * 1024 + k0 + col);
            *(short8*)((char*)Bt + row * 128 + ((col * 2) ^ ((row & 7) << 4))) = vb;
        }
        __syncthreads();
#pragma unroll
        for (int ks = 0; ks < 2; ++ks) {
            int bc = ks * 64 + lk * 16;
            int brow = w * 16 + l15;
            short8 bfr = *(const short8*)((char*)Bt + brow * 128 + (bc ^ ((brow & 7) << 4)));
#pragma unroll
            for (int m = 0; m < 4; ++m) {
                int arow = m * 16 + l15;
                short8 af = *(const short8*)((char*)At + arow * 128 + (bc ^ ((arow & 7) << 4)));
                acc[m] = __builtin_amdgcn_mfma_f32_16x16x32_bf16(af, bfr, acc[m], 0, 0, 0);
            }
        }
    }
#pragma unroll
    for (int m = 0; m < 4; ++m)
#pragma unroll
        for (int r = 0; r < 4; ++r) {
            int row = m0 + m * 16 + lk * 4 + r;
            int col = n0 + w * 16 + l15;
            C[(size_t)row * 1024 + col] = f2bf(acc[m][r]);
        }
}

// ---------------- fused dual GEMM, 8-phase schedule (r17): y = x@H + u ; v2t ----------------
__global__ __launch_bounds__(512) void gemm_yv(
    const u16* __restrict__ A, const u16* __restrict__ BH, const u16* __restrict__ BW,
    const float* __restrict__ ub, u16* __restrict__ Y, u16* __restrict__ V2t)
{
    __shared__ __align__(16) char smbuf[131072];
    char* A0 = smbuf;
    char* B0 = smbuf + 32768;
    char* A1 = smbuf + 65536;
    char* B1 = smbuf + 98304;

    const int t = threadIdx.x;
    const int lane = t & 63, w = t >> 6;
    const int l15 = lane & 15, lk = lane >> 4;
    const int wm = w >> 2, wn = w & 3;
    const int K = 1024;

    const int bid = blockIdx.y * 8 + blockIdx.x;   // nwg = 512
    const int swz = (bid & 7) * 64 + (bid >> 3);
    const int tn = swz & 7, tm = swz >> 3;
    const int m0 = tm * 256;
    const bool isv = tn >= 4;
    const int n0 = (tn & 3) * 256;
    const u16* B = isv ? BW : BH;

    const int srow = t >> 3;
    const int scg = ((t & 7) ^ (srow & 7)) * 8;

    f32x4 acc[8][4];
#pragma unroll
    for (int mf = 0; mf < 8; ++mf)
#pragma unroll
        for (int nf = 0; nf < 4; ++nf)
            acc[mf][nf] = (f32x4){0.f, 0.f, 0.f, 0.f};

    auto STAGE_T = [&](const u16* G, int gr0, int k0, char* dst) {
#pragma unroll
        for (int h = 0; h < 2; ++h)
#pragma unroll
            for (int c = 0; c < 2; ++c) {
                int ri = h * 128 + c * 64 + srow;
                gl_lds16(G + (size_t)(gr0 + ri) * K + k0 + scg,
                         (u16*)(dst + h * 16384 + c * 8192 + t * 16));
            }
    };
    auto RD = [&](const char* tile, int r, int kc) -> short8 {
        return *(const short8*)(tile + r * 128 + ((kc ^ (r & 7)) << 4));
    };

    short8 av[4], bv[4];
    auto LA = [&](const char* tA, int mfb, int ks) {
#pragma unroll
        for (int f = 0; f < 4; ++f)
            av[f] = RD(tA, wm * 128 + (mfb + f) * 16 + l15, ks * 4 + lk);
    };
    auto LB = [&](const char* tB, int ks) {
#pragma unroll
        for (int f = 0; f < 4; ++f)
            bv[f] = RD(tB, wn * 64 + f * 16 + l15, ks * 4 + lk);
    };
    auto MM = [&](int mfb) {
        __builtin_amdgcn_s_setprio(1);
#pragma unroll
        for (int f = 0; f < 4; ++f)
#pragma unroll
            for (int nf = 0; nf < 4; ++nf)
                acc[mfb + f][nf] = __builtin_amdgcn_mfma_f32_16x16x32_bf16(av[f], bv[nf], acc[mfb + f][nf], 0, 0, 0);
        __builtin_amdgcn_s_setprio(0);
    };
    auto BARW = [&] {
        __builtin_amdgcn_s_barrier();
        asm volatile("s_waitcnt lgkmcnt(0)" ::: "memory");
        __builtin_amdgcn_sched_barrier(0);
    };
    auto BARE = [&] {
        __builtin_amdgcn_s_barrier();
        __builtin_amdgcn_sched_barrier(0);
    };

    STAGE_T(A, m0, 0, A0);
    STAGE_T(B, n0, 0, B0);
    STAGE_T(A, m0, 64, A1);
    STAGE_T(B, n0, 64, B1);
    asm volatile("s_waitcnt vmcnt(8)" ::: "memory");
    __builtin_amdgcn_s_barrier();
    __builtin_amdgcn_sched_barrier(0);

    for (int j = 0; j < 8; ++j) {
        LA(A0, 0, 0); LB(B0, 0);
        if (j >= 1) STAGE_T(A, m0, (2 * j + 1) * 64, A1);
        BARW(); MM(0); BARE();
        LA(A0, 4, 0);
        BARW(); MM(4); BARE();
        LA(A0, 0, 1); LB(B0, 1);
        BARW(); MM(0); BARE();
        LA(A0, 4, 1);
        if (2 * j + 2 < 16) {
            STAGE_T(B, n0, (2 * j + 2) * 64, B0);
            asm volatile("s_waitcnt vmcnt(4)" ::: "memory");
        } else {
            asm volatile("s_waitcnt vmcnt(0)" ::: "memory");
        }
        BARW(); MM(4); BARE();
        LA(A1, 0, 0); LB(B1, 0);
        if (2 * j + 2 < 16) STAGE_T(A, m0, (2 * j + 2) * 64, A0);
        BARW(); MM(0); BARE();
        LA(A1, 4, 0);
        BARW(); MM(4); BARE();
        LA(A1, 0, 1); LB(B1, 1);
        BARW(); MM(0); BARE();
        LA(A1, 4, 1);
        if (2 * j + 3 < 16) {
            STAGE_T(B, n0, (2 * j + 3) * 64, B1);
            asm volatile("s_waitcnt vmcnt(4)" ::: "memory");
        } else {
            asm volatile("s_waitcnt vmcnt(0)" ::: "memory");
        }
        BARW(); MM(4); BARE();
    }

    if (!isv) {
#pragma unroll
        for (int mf = 0; mf < 8; ++mf)
#pragma unroll
            for (int nf = 0; nf < 4; ++nf) {
                int col = n0 + wn * 64 + nf * 16 + l15;
                float bvx = ub[col];
#pragma unroll
                for (int r = 0; r < 4; ++r) {
                    int row = m0 + wm * 128 + mf * 16 + lk * 4 + r;
                    Y[(size_t)row * 1024 + col] = f2bf(acc[mf][nf][r] + bvx);
                }
            }
    } else {
#pragma unroll
        for (int mf = 0; mf < 8; ++mf)
#pragma unroll
            for (int nf = 0; nf < 4; ++nf) {
                int col = n0 + wn * 64 + nf * 16 + l15;
                int row0 = m0 + wm * 128 + mf * 16 + lk * 4;
                short4v pk;
#pragma unroll
                for (int r = 0; r < 4; ++r) pk[r] = (short)f2bf(acc[mf][nf][r]);
                *(short4v*)(V2t + (size_t)col * 16384 + row0) = pk;
            }
    }
}

// ---------------- windowed causal attention, paired-chunk load balancing ----------------
// One block = window win, q-chunks c (rows c*32..) and 7-c (rows (7-c)*32..).
// kv extents: lo (c+1)*32, hi (8-c)*32 -> uniform 9 units/block. Grid 256.
// Col-tile -> wave mapping: tile = n*4 + wv (extent spreads across waves).
// acc m-tiles: 0-1 = lo chunk (LDS q-rows 0-31), 2-3 = hi chunk (rows 32-63).
__global__ __launch_bounds__(256, 1) void attn_win(
    const u16* __restrict__ y, const u16* __restrict__ xb,
    const u16* __restrict__ vt, const float* __restrict__ xres,
    const float* __restrict__ b2, float* __restrict__ outp)
{
    // [0,81920): staging dbuf, buf b at b*40960: Qt 8KB + Kt 32KB / Vl 32KB
    // [81920,114688): P bf16 [64][256] swizzled
    // [114688,115712): rmax [64][4] | [115712,116736): rsum [64][4]
    __shared__ __align__(16) char smem[116736];
    u16* P  = (u16*)(smem + 81920);
    float* rmax = (float*)(smem + 114688);
    float* rsum = (float*)(smem + 115712);

    const int t = threadIdx.x;
    const int lane = t & 63, wv = t >> 6;
    const int l15 = lane & 15, lk = lane >> 4;
    const int bid = blockIdx.x;
    const int swz = (bid & 7) * 32 + (bid >> 3);
    const int win = swz >> 2, c = swz & 3;
    const size_t qlo = (size_t)win * 256 + c * 32;
    const size_t qhi = (size_t)win * 256 + (7 - c) * 32;
    const size_t krow0 = (size_t)win * 256;
    const int kvx = (8 - c) * 32;            // staged kv extent (cols/rows)
    const int tlo = 2 * (c + 1);             // lo col-tile extent (16-col units)
    const int thi = 2 * (8 - c);             // hi col-tile extent

    f32x4 acc[4][4];
#pragma unroll
    for (int m = 0; m < 4; ++m)
#pragma unroll
        for (int n = 0; n < 4; ++n)
            acc[m][n] = (f32x4){0.f, 0.f, 0.f, 0.f};

    // ---- phase 1: scores over E=1024, 16 chunks, 2-deep dbuf pipeline ----
    short8 pq[2], pk[8];
    auto LOAD_QK = [&](int e0) {
#pragma unroll
        for (int p = 0; p < 2; ++p) {
            int e = p * 2048 + t * 8;
            int r = e >> 6;                  // 0..63; 0-31 lo, 32-63 hi
            size_t grow = (r < 32) ? (qlo + r) : (qhi + r - 32);
            pq[p] = *(const short8*)(y + grow * 1024 + e0 + (e & 63));
        }
#pragma unroll
        for (int p = 0; p < 8; ++p) {
            if (p * 32 < kvx) {
                int e = p * 2048 + t * 8;
                pk[p] = *(const short8*)(xb + (krow0 + (e >> 6)) * 1024 + e0 + (e & 63));
            }
        }
    };
    auto WRITE_QK = [&](int b) {
        char* Qt = smem + b * 40960;
        char* Kt = Qt + 8192;
#pragma unroll
        for (int p = 0; p < 2; ++p) {
            int e = p * 2048 + t * 8;
            int row = e >> 6, col = e & 63;
            *(short8*)(Qt + row * 128 + ((col * 2) ^ ((row & 7) << 4))) = pq[p];
        }
#pragma unroll
        for (int p = 0; p < 8; ++p) {
            if (p * 32 < kvx) {
                int e = p * 2048 + t * 8;
                int row = e >> 6, col = e & 63;
                *(short8*)(Kt + row * 128 + ((col * 2) ^ ((row & 7) << 4))) = pk[p];
            }
        }
    };

    LOAD_QK(0);
    WRITE_QK(0);
    LOAD_QK(64);
    __syncthreads();

    for (int i = 0; i < 16; ++i) {
        const int b = i & 1;
        if (i + 1 < 16) {
            WRITE_QK(b ^ 1);
            if (i + 2 < 16) LOAD_QK((i + 2) * 64);
        }
        const char* Qt = smem + b * 40960;
        const char* Kt = Qt + 8192;
#pragma unroll
        for (int ks = 0; ks < 2; ++ks) {
            const int bc = ks * 64 + lk * 16;
            short8 af[4];
#pragma unroll
            for (int m = 0; m < 4; ++m) {
                int row = m * 16 + l15;
                af[m] = *(const short8*)(Qt + row * 128 + (bc ^ ((row & 7) << 4)));
            }
            __builtin_amdgcn_s_setprio(1);
#pragma unroll
            for (int n = 0; n < 4; ++n) {
                int tile = n * 4 + wv;
                if (tile < thi) {
                    int row = tile * 16 + l15;
                    short8 bfr = *(const short8*)(Kt + row * 128 + (bc ^ ((row & 7) << 4)));
                    acc[2][n] = __builtin_amdgcn_mfma_f32_16x16x32_bf16(af[2], bfr, acc[2][n], 0, 0, 0);
                    acc[3][n] = __builtin_amdgcn_mfma_f32_16x16x32_bf16(af[3], bfr, acc[3][n], 0, 0, 0);
                    if (tile < tlo) {
                        acc[0][n] = __builtin_amdgcn_mfma_f32_16x16x32_bf16(af[0], bfr, acc[0][n], 0, 0, 0);
                        acc[1][n] = __builtin_amdgcn_mfma_f32_16x16x32_bf16(af[1], bfr, acc[1][n], 0, 0, 0);
                    }
                }
            }
            __builtin_amdgcn_s_setprio(0);
        }
        __syncthreads();
    }

    // ---- phase 2: register softmax (rows 0-31 lo, 32-63 hi) ----
#pragma unroll
    for (int m = 0; m < 4; ++m)
#pragma unroll
        for (int n = 0; n < 4; ++n) {
            int col = (n * 4 + wv) * 16 + l15;
#pragma unroll
            for (int r = 0; r < 4; ++r) {
                int qpos = (m < 2) ? (c * 32 + m * 16 + lk * 4 + r)
                                   : ((7 - c) * 32 + (m - 2) * 16 + lk * 4 + r);
                float v = acc[m][n][r] * 0.125f;
                acc[m][n][r] = (col <= qpos) ? v : -1e30f;
            }
        }
#pragma unroll
    for (int m = 0; m < 4; ++m)
#pragma unroll
        for (int r = 0; r < 4; ++r) {
            float tmx = fmaxf(fmaxf(acc[m][0][r], acc[m][1][r]), fmaxf(acc[m][2][r], acc[m][3][r]));
            tmx = fmaxf(tmx, __shfl_xor(tmx, 1));
            tmx = fmaxf(tmx, __shfl_xor(tmx, 2));
            tmx = fmaxf(tmx, __shfl_xor(tmx, 4));
            tmx = fmaxf(tmx, __shfl_xor(tmx, 8));
            if (l15 == 0) rmax[(m * 16 + lk * 4 + r) * 4 + wv] = tmx;
        }
    __syncthreads();
#pragma unroll
    for (int m = 0; m < 4; ++m)
#pragma unroll
        for (int r = 0; r < 4; ++r) {
            int row = m * 16 + lk * 4 + r;
            float m4 = fmaxf(fmaxf(rmax[row * 4], rmax[row * 4 + 1]),
                             fmaxf(rmax[row * 4 + 2], rmax[row * 4 + 3]));
            float s = 0.f;
#pragma unroll
            for (int n = 0; n < 4; ++n) {
                float e = __expf(acc[m][n][r] - m4);
                acc[m][n][r] = e;
                s += e;
            }
            s += __shfl_xor(s, 1);
            s += __shfl_xor(s, 2);
            s += __shfl_xor(s, 4);
            s += __shfl_xor(s, 8);
            if (l15 == 0) rsum[row * 4 + wv] = s;
        }
    __syncthreads();
#pragma unroll
    for (int m = 0; m < 4; ++m)
#pragma unroll
        for (int r = 0; r < 4; ++r) {
            int row = m * 16 + lk * 4 + r;
            float inv = 1.f / (rsum[row * 4] + rsum[row * 4 + 1] + rsum[row * 4 + 2] + rsum[row * 4 + 3]);
#pragma unroll
            for (int n = 0; n < 4; ++n) {
                int col = (n * 4 + wv) * 16 + l15;
                *(u16*)((char*)P + row * 512 + ((col * 2) ^ ((row & 7) << 4))) = f2bf(acc[m][n][r] * inv);
            }
        }

    // ---- phase 3: out = attn @ v2 + b2 + x, 16 chunks, 2-deep dbuf, ks-skip ----
    short8 pv[8];
    auto LOAD_V = [&](int n0) {
#pragma unroll
        for (int p = 0; p < 8; ++p) {
            int e = p * 2048 + t * 8;
            if ((e & 255) < kvx)
                pv[p] = *(const short8*)(vt + (size_t)(n0 + (e >> 8)) * 16384 + win * 256 + (e & 255));
        }
    };
    auto WRITE_V = [&](int b) {
        char* Vl = smem + b * 40960;
#pragma unroll
        for (int p = 0; p < 8; ++p) {
            int e = p * 2048 + t * 8;
            if ((e & 255) < kvx) {
                int row = e >> 8, col = e & 255;
                *(short8*)(Vl + row * 512 + ((col * 2) ^ ((row & 7) << 4))) = pv[p];
            }
        }
    };

    LOAD_V(0);
    WRITE_V(0);
    LOAD_V(64);
    __syncthreads();

    for (int i = 0; i < 16; ++i) {
        const int b = i & 1;
        const int n0 = i * 64;
        if (i + 1 < 16) {
            WRITE_V(b ^ 1);
            if (i + 2 < 16) LOAD_V((i + 2) * 64);
        }
        const char* Vl = smem + b * 40960;
        f32x4 acc2[4];
#pragma unroll
        for (int m = 0; m < 4; ++m) acc2[m] = (f32x4){0.f, 0.f, 0.f, 0.f};
#pragma unroll
        for (int ks = 0; ks < 8; ++ks) {
            if (ks < 8 - c) {
                const int bc = ks * 64 + lk * 16;
                short8 af[4];
#pragma unroll
                for (int m = 0; m < 4; ++m) {
                    int row = m * 16 + l15;
                    af[m] = *(const short8*)((char*)P + row * 512 + (bc ^ ((row & 7) << 4)));
                }
                int vrow = wv * 16 + l15;
                short8 bfr = *(const short8*)(Vl + vrow * 512 + (bc ^ ((vrow & 7) << 4)));
                __builtin_amdgcn_s_setprio(1);
                acc2[2] = __builtin_amdgcn_mfma_f32_16x16x32_bf16(af[2], bfr, acc2[2], 0, 0, 0);
                acc2[3] = __builtin_amdgcn_mfma_f32_16x16x32_bf16(af[3], bfr, acc2[3], 0, 0, 0);
                if (ks < c + 1) {
                    acc2[0] = __builtin_amdgcn_mfma_f32_16x16x32_bf16(af[0], bfr, acc2[0], 0, 0, 0);
                    acc2[1] = __builtin_amdgcn_mfma_f32_16x16x32_bf16(af[1], bfr, acc2[1], 0, 0, 0);
                }
                __builtin_amdgcn_s_setprio(0);
            }
        }
#pragma unroll
        for (int m = 0; m < 4; ++m) {
#pragma unroll
            for (int r = 0; r < 4; ++r) {
                int lrow = (m < 2) ? (m * 16 + lk * 4 + r) : ((m - 2) * 16 + lk * 4 + r);
                size_t grow = (m < 2) ? (qlo + lrow) : (qhi + lrow);
                int col = n0 + wv * 16 + l15;
                size_t idx = grow * 1024 + col;
                outp[idx] = acc2[m][r] + b2[col] + xres[idx];
            }
        }
        __syncthreads();
    }
}

extern "C" void kernel_launch(void* const* d_in, const int* in_sizes, int n_in,
                              void* d_out, int out_size, void* d_ws, size_t ws_size,
                              hipStream_t stream) {
    const float* x  = (const float*)d_in[0];
    const float* Wq = (const float*)d_in[1];
    const float* bq = (const float*)d_in[2];
    const float* Wk = (const float*)d_in[3];
    // bk (d_in[4]) contributes only row-constants to scores -> cancels in softmax
    const float* Wv = (const float*)d_in[5];
    const float* bv = (const float*)d_in[6];
    const float* Wo = (const float*)d_in[7];
    const float* bo = (const float*)d_in[8];
    float* out = (float*)d_out;

    char* ws = (char*)d_ws;
    u16* xb  = (u16*)(ws);                    // [16384,1024] bf16
    u16* yb  = (u16*)(ws + 33554432);         // [16384,1024] bf16
    u16* v2t = (u16*)(ws + 67108864);         // [1024,16384] bf16 (v2 transposed)
    u16* WqT = (u16*)(ws + 100663296);        // [1024,1024] bf16
    u16* WkT = (u16*)(ws + 102760448);        // [1024,1024] bf16
    u16* WvT = (u16*)(ws + 104857600);        // [1024,1024] bf16
    u16* Wob = (u16*)(ws + 106954752);        // [1024,1024] bf16
    u16* Hb  = (u16*)(ws + 109051904);        // [1024,1024] bf16 H = Wk^T Wq
    u16* W2b = (u16*)(ws + 111149056);        // [1024,1024] bf16 W2 = Wo Wv
    float* u_  = (float*)(ws + 113246208);    // [1024] fp32
    float* b2_ = (float*)(ws + 113250304);    // [1024] fp32

    prep<<<9284, 256, 0, stream>>>(x, xb, Wq, Wk, Wv, Wo, WqT, WkT, WvT, Wob,
                                   bq, bv, bo, u_, b2_);
    gemm_small_dual<<<512, 256, 0, stream>>>(WkT, WqT, Hb, Wob, WvT, W2b);
    gemm_yv<<<dim3(8, 64), 512, 0, stream>>>(xb, Hb, W2b, u_, yb, v2t);
    attn_win<<<256, 256, 0, stream>>>(yb, xb, v2t, x, b2_, out);
}

// Round 19
// 189.644 us; speedup vs baseline: 1.0513x; 1.0137x over previous
//
#include <hip/hip_runtime.h>
#include <hip/hip_bf16.h>

// LocalSelfAttention: B=4, S=4096, E=1024, WINDOW=256, SCALE=0.125
// Algebra: scores_ij = (x G + u)_i . x_j (row-consts cancel in softmax),
//   G = Wq^T Wk, u = Wk^T bq.  Since attn rows sum to 1:
//   out = attn @ (x W2^T) + b2 + x,  W2 = Wo Wv, b2 = Wo bv + bo.
// Round 19: attn residual read from bf16 xb (saves 33.5 MB fp32-x reads).
//   Everything else frozen at r18 (balanced attn, 8-phase gemm, fused prep).

typedef unsigned short u16;
typedef __attribute__((ext_vector_type(8))) short short8;   // 8 bf16
typedef __attribute__((ext_vector_type(4))) short short4v;  // 4 bf16 (8B)
typedef __attribute__((ext_vector_type(4))) float f32x4;

__device__ __forceinline__ u16 f2bf(float f) {
    __hip_bfloat16 h = __float2bfloat16(f);
    return __builtin_bit_cast(u16, h);
}

__device__ __forceinline__ float bf2f(u16 v) {
    unsigned int u = ((unsigned int)v) << 16;
    return __builtin_bit_cast(float, u);
}

__device__ __forceinline__ void gl_lds16(const u16* g, u16* l) {
    __builtin_amdgcn_global_load_lds(
        (const __attribute__((address_space(1))) void*)g,
        (__attribute__((address_space(3))) void*)l,
        16, 0, 0);
}

// ---------------- fused prep: cast x | wcast (WqT,WkT,WvT,Wob) | u,b2 ----------------
__global__ void prep(const float* __restrict__ x, u16* __restrict__ xb,
                     const float* __restrict__ Wq, const float* __restrict__ Wk,
                     const float* __restrict__ Wv, const float* __restrict__ Wo,
                     u16* __restrict__ WqT, u16* __restrict__ WkT,
                     u16* __restrict__ WvT, u16* __restrict__ Wob,
                     const float* __restrict__ bq, const float* __restrict__ bv,
                     const float* __restrict__ bo,
                     float* __restrict__ u, float* __restrict__ b2)
{
    __shared__ float lt[64][65];
    const int t = threadIdx.x;
    const int blk = blockIdx.x;
    if (blk < 8192) {
        int i = (blk * 256 + t) * 8;
        const float4* s = (const float4*)(x + i);
        float4 a = s[0], b = s[1];
        short8 o;
        o[0] = (short)f2bf(a.x); o[1] = (short)f2bf(a.y); o[2] = (short)f2bf(a.z); o[3] = (short)f2bf(a.w);
        o[4] = (short)f2bf(b.x); o[5] = (short)f2bf(b.y); o[6] = (short)f2bf(b.z); o[7] = (short)f2bf(b.w);
        *(short8*)(xb + i) = o;
        return;
    }
    if (blk < 9216) {
        const int wb = blk - 8192;
        const int which = wb >> 8;
        const int bid = wb & 255;
        const int c0 = (bid & 15) * 64, r0 = (bid >> 4) * 64;
        const int tr = t >> 3, tc = (t & 7) * 8;
        const float* src = which == 0 ? Wq : which == 1 ? Wk : which == 2 ? Wv : Wo;
        if (which == 3) {
#pragma unroll
            for (int p = 0; p < 2; ++p) {
                int r = p * 32 + tr;
                const float* s = src + (size_t)(r0 + r) * 1024 + c0 + tc;
                float4 a = *(const float4*)s, b = *(const float4*)(s + 4);
                short8 o;
                o[0] = (short)f2bf(a.x); o[1] = (short)f2bf(a.y); o[2] = (short)f2bf(a.z); o[3] = (short)f2bf(a.w);
                o[4] = (short)f2bf(b.x); o[5] = (short)f2bf(b.y); o[6] = (short)f2bf(b.z); o[7] = (short)f2bf(b.w);
                *(short8*)(Wob + (size_t)(r0 + r) * 1024 + c0 + tc) = o;
            }
            return;
        }
        u16* dst = which == 0 ? WqT : which == 1 ? WkT : WvT;
#pragma unroll
        for (int p = 0; p < 2; ++p) {
            int r = p * 32 + tr;
            const float* s = src + (size_t)(r0 + r) * 1024 + c0 + tc;
            float4 a = *(const float4*)s, b = *(const float4*)(s + 4);
            lt[r][tc + 0] = a.x; lt[r][tc + 1] = a.y; lt[r][tc + 2] = a.z; lt[r][tc + 3] = a.w;
            lt[r][tc + 4] = b.x; lt[r][tc + 5] = b.y; lt[r][tc + 6] = b.z; lt[r][tc + 7] = b.w;
        }
        __syncthreads();
#pragma unroll
        for (int p = 0; p < 2; ++p) {
            int r = p * 32 + tr;
            short8 o;
#pragma unroll
            for (int j = 0; j < 8; ++j) o[j] = (short)f2bf(lt[tc + j][r]);
            *(short8*)(dst + (size_t)(c0 + r) * 1024 + r0 + tc) = o;
        }
        return;
    }
    {
        const int bid = blk - 9216;
        if (bid < 4) {
            int b = bid * 256 + t;
            float acc = 0.f;
            for (int o = 0; o < 1024; ++o) acc += Wk[(size_t)o * 1024 + b] * bq[o];
            u[b] = acc;
        } else {
            int n = (bid - 4) * 16 + (t >> 4);
            int l = t & 15;
            float acc = 0.f;
            for (int m = l; m < 1024; m += 16) acc += Wo[(size_t)n * 1024 + m] * bv[m];
#pragma unroll
            for (int s = 1; s < 16; s <<= 1) acc += __shfl_xor(acc, s, 64);
            if (l == 0) b2[n] = acc + bo[n];
        }
    }
}

// ---------------- dual small GEMM (1024^3): H = WkT @ WqT^T, W2 = Wob @ WvT^T ----------------
__global__ __launch_bounds__(256, 4) void gemm_small_dual(
    const u16* __restrict__ HA, const u16* __restrict__ HB, u16* __restrict__ HC,
    const u16* __restrict__ WA, const u16* __restrict__ WB, u16* __restrict__ WC)
{
    __shared__ __align__(16) u16 At[64 * 64], Bt[64 * 64];
    const bool sec = blockIdx.x >= 256;
    const u16* A = sec ? WA : HA;
    const u16* B = sec ? WB : HB;
    u16* C = sec ? WC : HC;
    const int bid = blockIdx.x & 255;
    const int m0 = (bid >> 4) * 64, n0 = (bid & 15) * 64;
    const int t = threadIdx.x, lane = t & 63, w = t >> 6;
    const int l15 = lane & 15, lk = lane >> 4;

    f32x4 acc[4];
#pragma unroll
    for (int m = 0; m < 4; ++m) acc[m] = (f32x4){0.f, 0.f, 0.f, 0.f};

    for (int k0 = 0; k0 < 1024; k0 += 64) {
        __syncthreads();
#pragma unroll
        for (int p = 0; p < 2; ++p) {
            int e = p * 2048 + t * 8;
            int row = e >> 6, col = e & 63;
            short8 va = *(const short8*)(A + (size_t)(m0 + row) * 1024 + k0 + col);
            *(short8*)((char*)At + row * 128 + ((col * 2) ^ ((row & 7) << 4))) = va;
            short8 vb = *(const short8*)(B + (size_t)(n0 + row) * 1024 + k0 + col);
            *(short8*)((char*)Bt + row * 128 + ((col * 2) ^ ((row & 7) << 4))) = vb;
        }
        __syncthreads();
#pragma unroll
        for (int ks = 0; ks < 2; ++ks) {
            int bc = ks * 64 + lk * 16;
            int brow = w * 16 + l15;
            short8 bfr = *(const short8*)((char*)Bt + brow * 128 + (bc ^ ((brow & 7) << 4)));
#pragma unroll
            for (int m = 0; m < 4; ++m) {
                int arow = m * 16 + l15;
                short8 af = *(const short8*)((char*)At + arow * 128 + (bc ^ ((arow & 7) << 4)));
                acc[m] = __builtin_amdgcn_mfma_f32_16x16x32_bf16(af, bfr, acc[m], 0, 0, 0);
            }
        }
    }
#pragma unroll
    for (int m = 0; m < 4; ++m)
#pragma unroll
        for (int r = 0; r < 4; ++r) {
            int row = m0 + m * 16 + lk * 4 + r;
            int col = n0 + w * 16 + l15;
            C[(size_t)row * 1024 + col] = f2bf(acc[m][r]);
        }
}

// ---------------- fused dual GEMM, 8-phase schedule (r17): y = x@H + u ; v2t ----------------
__global__ __launch_bounds__(512) void gemm_yv(
    const u16* __restrict__ A, const u16* __restrict__ BH, const u16* __restrict__ BW,
    const float* __restrict__ ub, u16* __restrict__ Y, u16* __restrict__ V2t)
{
    __shared__ __align__(16) char smbuf[131072];
    char* A0 = smbuf;
    char* B0 = smbuf + 32768;
    char* A1 = smbuf + 65536;
    char* B1 = smbuf + 98304;

    const int t = threadIdx.x;
    const int lane = t & 63, w = t >> 6;
    const int l15 = lane & 15, lk = lane >> 4;
    const int wm = w >> 2, wn = w & 3;
    const int K = 1024;

    const int bid = blockIdx.y * 8 + blockIdx.x;   // nwg = 512
    const int swz = (bid & 7) * 64 + (bid >> 3);
    const int tn = swz & 7, tm = swz >> 3;
    const int m0 = tm * 256;
    const bool isv = tn >= 4;
    const int n0 = (tn & 3) * 256;
    const u16* B = isv ? BW : BH;

    const int srow = t >> 3;
    const int scg = ((t & 7) ^ (srow & 7)) * 8;

    f32x4 acc[8][4];
#pragma unroll
    for (int mf = 0; mf < 8; ++mf)
#pragma unroll
        for (int nf = 0; nf < 4; ++nf)
            acc[mf][nf] = (f32x4){0.f, 0.f, 0.f, 0.f};

    auto STAGE_T = [&](const u16* G, int gr0, int k0, char* dst) {
#pragma unroll
        for (int h = 0; h < 2; ++h)
#pragma unroll
            for (int c = 0; c < 2; ++c) {
                int ri = h * 128 + c * 64 + srow;
                gl_lds16(G + (size_t)(gr0 + ri) * K + k0 + scg,
                         (u16*)(dst + h * 16384 + c * 8192 + t * 16));
            }
    };
    auto RD = [&](const char* tile, int r, int kc) -> short8 {
        return *(const short8*)(tile + r * 128 + ((kc ^ (r & 7)) << 4));
    };

    short8 av[4], bv[4];
    auto LA = [&](const char* tA, int mfb, int ks) {
#pragma unroll
        for (int f = 0; f < 4; ++f)
            av[f] = RD(tA, wm * 128 + (mfb + f) * 16 + l15, ks * 4 + lk);
    };
    auto LB = [&](const char* tB, int ks) {
#pragma unroll
        for (int f = 0; f < 4; ++f)
            bv[f] = RD(tB, wn * 64 + f * 16 + l15, ks * 4 + lk);
    };
    auto MM = [&](int mfb) {
        __builtin_amdgcn_s_setprio(1);
#pragma unroll
        for (int f = 0; f < 4; ++f)
#pragma unroll
            for (int nf = 0; nf < 4; ++nf)
                acc[mfb + f][nf] = __builtin_amdgcn_mfma_f32_16x16x32_bf16(av[f], bv[nf], acc[mfb + f][nf], 0, 0, 0);
        __builtin_amdgcn_s_setprio(0);
    };
    auto BARW = [&] {
        __builtin_amdgcn_s_barrier();
        asm volatile("s_waitcnt lgkmcnt(0)" ::: "memory");
        __builtin_amdgcn_sched_barrier(0);
    };
    auto BARE = [&] {
        __builtin_amdgcn_s_barrier();
        __builtin_amdgcn_sched_barrier(0);
    };

    STAGE_T(A, m0, 0, A0);
    STAGE_T(B, n0, 0, B0);
    STAGE_T(A, m0, 64, A1);
    STAGE_T(B, n0, 64, B1);
    asm volatile("s_waitcnt vmcnt(8)" ::: "memory");
    __builtin_amdgcn_s_barrier();
    __builtin_amdgcn_sched_barrier(0);

    for (int j = 0; j < 8; ++j) {
        LA(A0, 0, 0); LB(B0, 0);
        if (j >= 1) STAGE_T(A, m0, (2 * j + 1) * 64, A1);
        BARW(); MM(0); BARE();
        LA(A0, 4, 0);
        BARW(); MM(4); BARE();
        LA(A0, 0, 1); LB(B0, 1);
        BARW(); MM(0); BARE();
        LA(A0, 4, 1);
        if (2 * j + 2 < 16) {
            STAGE_T(B, n0, (2 * j + 2) * 64, B0);
            asm volatile("s_waitcnt vmcnt(4)" ::: "memory");
        } else {
            asm volatile("s_waitcnt vmcnt(0)" ::: "memory");
        }
        BARW(); MM(4); BARE();
        LA(A1, 0, 0); LB(B1, 0);
        if (2 * j + 2 < 16) STAGE_T(A, m0, (2 * j + 2) * 64, A0);
        BARW(); MM(0); BARE();
        LA(A1, 4, 0);
        BARW(); MM(4); BARE();
        LA(A1, 0, 1); LB(B1, 1);
        BARW(); MM(0); BARE();
        LA(A1, 4, 1);
        if (2 * j + 3 < 16) {
            STAGE_T(B, n0, (2 * j + 3) * 64, B1);
            asm volatile("s_waitcnt vmcnt(4)" ::: "memory");
        } else {
            asm volatile("s_waitcnt vmcnt(0)" ::: "memory");
        }
        BARW(); MM(4); BARE();
    }

    if (!isv) {
#pragma unroll
        for (int mf = 0; mf < 8; ++mf)
#pragma unroll
            for (int nf = 0; nf < 4; ++nf) {
                int col = n0 + wn * 64 + nf * 16 + l15;
                float bvx = ub[col];
#pragma unroll
                for (int r = 0; r < 4; ++r) {
                    int row = m0 + wm * 128 + mf * 16 + lk * 4 + r;
                    Y[(size_t)row * 1024 + col] = f2bf(acc[mf][nf][r] + bvx);
                }
            }
    } else {
#pragma unroll
        for (int mf = 0; mf < 8; ++mf)
#pragma unroll
            for (int nf = 0; nf < 4; ++nf) {
                int col = n0 + wn * 64 + nf * 16 + l15;
                int row0 = m0 + wm * 128 + mf * 16 + lk * 4;
                short4v pk;
#pragma unroll
                for (int r = 0; r < 4; ++r) pk[r] = (short)f2bf(acc[mf][nf][r]);
                *(short4v*)(V2t + (size_t)col * 16384 + row0) = pk;
            }
    }
}

// ---------------- windowed causal attention, paired-chunk load balancing (r18) ----------------
// Residual now read from bf16 xb.
__global__ __launch_bounds__(256, 1) void attn_win(
    const u16* __restrict__ y, const u16* __restrict__ xb,
    const u16* __restrict__ vt,
    const float* __restrict__ b2, float* __restrict__ outp)
{
    __shared__ __align__(16) char smem[116736];
    u16* P  = (u16*)(smem + 81920);
    float* rmax = (float*)(smem + 114688);
    float* rsum = (float*)(smem + 115712);

    const int t = threadIdx.x;
    const int lane = t & 63, wv = t >> 6;
    const int l15 = lane & 15, lk = lane >> 4;
    const int bid = blockIdx.x;
    const int swz = (bid & 7) * 32 + (bid >> 3);
    const int win = swz >> 2, c = swz & 3;
    const size_t qlo = (size_t)win * 256 + c * 32;
    const size_t qhi = (size_t)win * 256 + (7 - c) * 32;
    const size_t krow0 = (size_t)win * 256;
    const int kvx = (8 - c) * 32;
    const int tlo = 2 * (c + 1);
    const int thi = 2 * (8 - c);

    f32x4 acc[4][4];
#pragma unroll
    for (int m = 0; m < 4; ++m)
#pragma unroll
        for (int n = 0; n < 4; ++n)
            acc[m][n] = (f32x4){0.f, 0.f, 0.f, 0.f};

    // ---- phase 1: scores over E=1024, 16 chunks, 2-deep dbuf pipeline ----
    short8 pq[2], pk[8];
    auto LOAD_QK = [&](int e0) {
#pragma unroll
        for (int p = 0; p < 2; ++p) {
            int e = p * 2048 + t * 8;
            int r = e >> 6;
            size_t grow = (r < 32) ? (qlo + r) : (qhi + r - 32);
            pq[p] = *(const short8*)(y + grow * 1024 + e0 + (e & 63));
        }
#pragma unroll
        for (int p = 0; p < 8; ++p) {
            if (p * 32 < kvx) {
                int e = p * 2048 + t * 8;
                pk[p] = *(const short8*)(xb + (krow0 + (e >> 6)) * 1024 + e0 + (e & 63));
            }
        }
    };
    auto WRITE_QK = [&](int b) {
        char* Qt = smem + b * 40960;
        char* Kt = Qt + 8192;
#pragma unroll
        for (int p = 0; p < 2; ++p) {
            int e = p * 2048 + t * 8;
            int row = e >> 6, col = e & 63;
            *(short8*)(Qt + row * 128 + ((col * 2) ^ ((row & 7) << 4))) = pq[p];
        }
#pragma unroll
        for (int p = 0; p < 8; ++p) {
            if (p * 32 < kvx) {
                int e = p * 2048 + t * 8;
                int row = e >> 6, col = e & 63;
                *(short8*)(Kt + row * 128 + ((col * 2) ^ ((row & 7) << 4))) = pk[p];
            }
        }
    };

    LOAD_QK(0);
    WRITE_QK(0);
    LOAD_QK(64);
    __syncthreads();

    for (int i = 0; i < 16; ++i) {
        const int b = i & 1;
        if (i + 1 < 16) {
            WRITE_QK(b ^ 1);
            if (i + 2 < 16) LOAD_QK((i + 2) * 64);
        }
        const char* Qt = smem + b * 40960;
        const char* Kt = Qt + 8192;
#pragma unroll
        for (int ks = 0; ks < 2; ++ks) {
            const int bc = ks * 64 + lk * 16;
            short8 af[4];
#pragma unroll
            for (int m = 0; m < 4; ++m) {
                int row = m * 16 + l15;
                af[m] = *(const short8*)(Qt + row * 128 + (bc ^ ((row & 7) << 4)));
            }
            __builtin_amdgcn_s_setprio(1);
#pragma unroll
            for (int n = 0; n < 4; ++n) {
                int tile = n * 4 + wv;
                if (tile < thi) {
                    int row = tile * 16 + l15;
                    short8 bfr = *(const short8*)(Kt + row * 128 + (bc ^ ((row & 7) << 4)));
                    acc[2][n] = __builtin_amdgcn_mfma_f32_16x16x32_bf16(af[2], bfr, acc[2][n], 0, 0, 0);
                    acc[3][n] = __builtin_amdgcn_mfma_f32_16x16x32_bf16(af[3], bfr, acc[3][n], 0, 0, 0);
                    if (tile < tlo) {
                        acc[0][n] = __builtin_amdgcn_mfma_f32_16x16x32_bf16(af[0], bfr, acc[0][n], 0, 0, 0);
                        acc[1][n] = __builtin_amdgcn_mfma_f32_16x16x32_bf16(af[1], bfr, acc[1][n], 0, 0, 0);
                    }
                }
            }
            __builtin_amdgcn_s_setprio(0);
        }
        __syncthreads();
    }

    // ---- phase 2: register softmax ----
#pragma unroll
    for (int m = 0; m < 4; ++m)
#pragma unroll
        for (int n = 0; n < 4; ++n) {
            int col = (n * 4 + wv) * 16 + l15;
#pragma unroll
            for (int r = 0; r < 4; ++r) {
                int qpos = (m < 2) ? (c * 32 + m * 16 + lk * 4 + r)
                                   : ((7 - c) * 32 + (m - 2) * 16 + lk * 4 + r);
                float v = acc[m][n][r] * 0.125f;
                acc[m][n][r] = (col <= qpos) ? v : -1e30f;
            }
        }
#pragma unroll
    for (int m = 0; m < 4; ++m)
#pragma unroll
        for (int r = 0; r < 4; ++r) {
            float tmx = fmaxf(fmaxf(acc[m][0][r], acc[m][1][r]), fmaxf(acc[m][2][r], acc[m][3][r]));
            tmx = fmaxf(tmx, __shfl_xor(tmx, 1));
            tmx = fmaxf(tmx, __shfl_xor(tmx, 2));
            tmx = fmaxf(tmx, __shfl_xor(tmx, 4));
            tmx = fmaxf(tmx, __shfl_xor(tmx, 8));
            if (l15 == 0) rmax[(m * 16 + lk * 4 + r) * 4 + wv] = tmx;
        }
    __syncthreads();
#pragma unroll
    for (int m = 0; m < 4; ++m)
#pragma unroll
        for (int r = 0; r < 4; ++r) {
            int row = m * 16 + lk * 4 + r;
            float m4 = fmaxf(fmaxf(rmax[row * 4], rmax[row * 4 + 1]),
                             fmaxf(rmax[row * 4 + 2], rmax[row * 4 + 3]));
            float s = 0.f;
#pragma unroll
            for (int n = 0; n < 4; ++n) {
                float e = __expf(acc[m][n][r] - m4);
                acc[m][n][r] = e;
                s += e;
            }
            s += __shfl_xor(s, 1);
            s += __shfl_xor(s, 2);
            s += __shfl_xor(s, 4);
            s += __shfl_xor(s, 8);
            if (l15 == 0) rsum[row * 4 + wv] = s;
        }
    __syncthreads();
#pragma unroll
    for (int m = 0; m < 4; ++m)
#pragma unroll
        for (int r = 0; r < 4; ++r) {
            int row = m * 16 + lk * 4 + r;
            float inv = 1.f / (rsum[row * 4] + rsum[row * 4 + 1] + rsum[row * 4 + 2] + rsum[row * 4 + 3]);
#pragma unroll
            for (int n = 0; n < 4; ++n) {
                int col = (n * 4 + wv) * 16 + l15;
                *(u16*)((char*)P + row * 512 + ((col * 2) ^ ((row & 7) << 4))) = f2bf(acc[m][n][r] * inv);
            }
        }

    // ---- phase 3: out = attn @ v2 + b2 + x (bf16 resid), 16 chunks, dbuf, ks-skip ----
    short8 pv[8];
    auto LOAD_V = [&](int n0) {
#pragma unroll
        for (int p = 0; p < 8; ++p) {
            int e = p * 2048 + t * 8;
            if ((e & 255) < kvx)
                pv[p] = *(const short8*)(vt + (size_t)(n0 + (e >> 8)) * 16384 + win * 256 + (e & 255));
        }
    };
    auto WRITE_V = [&](int b) {
        char* Vl = smem + b * 40960;
#pragma unroll
        for (int p = 0; p < 8; ++p) {
            int e = p * 2048 + t * 8;
            if ((e & 255) < kvx) {
                int row = e >> 8, col = e & 255;
                *(short8*)(Vl + row * 512 + ((col * 2) ^ ((row & 7) << 4))) = pv[p];
            }
        }
    };

    LOAD_V(0);
    WRITE_V(0);
    LOAD_V(64);
    __syncthreads();

    for (int i = 0; i < 16; ++i) {
        const int b = i & 1;
        const int n0 = i * 64;
        if (i + 1 < 16) {
            WRITE_V(b ^ 1);
            if (i + 2 < 16) LOAD_V((i + 2) * 64);
        }
        const char* Vl = smem + b * 40960;
        f32x4 acc2[4];
#pragma unroll
        for (int m = 0; m < 4; ++m) acc2[m] = (f32x4){0.f, 0.f, 0.f, 0.f};
#pragma unroll
        for (int ks = 0; ks < 8; ++ks) {
            if (ks < 8 - c) {
                const int bc = ks * 64 + lk * 16;
                short8 af[4];
#pragma unroll
                for (int m = 0; m < 4; ++m) {
                    int row = m * 16 + l15;
                    af[m] = *(const short8*)((char*)P + row * 512 + (bc ^ ((row & 7) << 4)));
                }
                int vrow = wv * 16 + l15;
                short8 bfr = *(const short8*)(Vl + vrow * 512 + (bc ^ ((vrow & 7) << 4)));
                __builtin_amdgcn_s_setprio(1);
                acc2[2] = __builtin_amdgcn_mfma_f32_16x16x32_bf16(af[2], bfr, acc2[2], 0, 0, 0);
                acc2[3] = __builtin_amdgcn_mfma_f32_16x16x32_bf16(af[3], bfr, acc2[3], 0, 0, 0);
                if (ks < c + 1) {
                    acc2[0] = __builtin_amdgcn_mfma_f32_16x16x32_bf16(af[0], bfr, acc2[0], 0, 0, 0);
                    acc2[1] = __builtin_amdgcn_mfma_f32_16x16x32_bf16(af[1], bfr, acc2[1], 0, 0, 0);
                }
                __builtin_amdgcn_s_setprio(0);
            }
        }
#pragma unroll
        for (int m = 0; m < 4; ++m) {
#pragma unroll
            for (int r = 0; r < 4; ++r) {
                int lrow = (m < 2) ? (m * 16 + lk * 4 + r) : ((m - 2) * 16 + lk * 4 + r);
                size_t grow = (m < 2) ? (qlo + lrow) : (qhi + lrow);
                int col = n0 + wv * 16 + l15;
                size_t idx = grow * 1024 + col;
                outp[idx] = acc2[m][r] + b2[col] + bf2f(xb[idx]);
            }
        }
        __syncthreads();
    }
}

extern "C" void kernel_launch(void* const* d_in, const int* in_sizes, int n_in,
                              void* d_out, int out_size, void* d_ws, size_t ws_size,
                              hipStream_t stream) {
    const float* x  = (const float*)d_in[0];
    const float* Wq = (const float*)d_in[1];
    const float* bq = (const float*)d_in[2];
    const float* Wk = (const float*)d_in[3];
    // bk (d_in[4]) contributes only row-constants to scores -> cancels in softmax
    const float* Wv = (const float*)d_in[5];
    const float* bv = (const float*)d_in[6];
    const float* Wo = (const float*)d_in[7];
    const float* bo = (const float*)d_in[8];
    float* out = (float*)d_out;

    char* ws = (char*)d_ws;
    u16* xb  = (u16*)(ws);                    // [16384,1024] bf16
    u16* yb  = (u16*)(ws + 33554432);         // [16384,1024] bf16
    u16* v2t = (u16*)(ws + 67108864);         // [1024,16384] bf16 (v2 transposed)
    u16* WqT = (u16*)(ws + 100663296);        // [1024,1024] bf16
    u16* WkT = (u16*)(ws + 102760448);        // [1024,1024] bf16
    u16* WvT = (u16*)(ws + 104857600);        // [1024,1024] bf16
    u16* Wob = (u16*)(ws + 106954752);        // [1024,1024] bf16
    u16* Hb  = (u16*)(ws + 109051904);        // [1024,1024] bf16 H = Wk^T Wq
    u16* W2b = (u16*)(ws + 111149056);        // [1024,1024] bf16 W2 = Wo Wv
    float* u_  = (float*)(ws + 113246208);    // [1024] fp32
    float* b2_ = (float*)(ws + 113250304);    // [1024] fp32

    prep<<<9284, 256, 0, stream>>>(x, xb, Wq, Wk, Wv, Wo, WqT, WkT, WvT, Wob,
                                   bq, bv, bo, u_, b2_);
    gemm_small_dual<<<512, 256, 0, stream>>>(WkT, WqT, Hb, Wob, WvT, W2b);
    gemm_yv<<<dim3(8, 64), 512, 0, stream>>>(xb, Hb, W2b, u_, yb, v2t);
    attn_win<<<256, 256, 0, stream>>>(yb, xb, v2t, b2_, out);
}